// Round 1
// baseline (538.005 us; speedup 1.0000x reference)
//
#include <hip/hip_runtime.h>

#define NN 512
#define NP (NN*NN)
#define LN_EPS 1e-5f

typedef __attribute__((ext_vector_type(8))) short short8;
typedef __attribute__((ext_vector_type(4))) float float4v;

__device__ __forceinline__ short f2bf(float x){
  union { float f; unsigned u; } un; un.f = x;
  unsigned r = un.u + 0x7fffu + ((un.u >> 16) & 1u);
  return (short)(r >> 16);
}
__device__ __forceinline__ float bf2f(short b){
  union { unsigned u; float f; } un; un.u = ((unsigned)(unsigned short)b) << 16;
  return un.f;
}
__device__ __forceinline__ float sigmoidf_(float x){ return 1.f/(1.f+__expf(-x)); }

// ---------------- prep: convert weights to bf16, interleave lrp/gate ----------
__global__ __launch_bounds__(256) void prep_kernel(
    const float* __restrict__ lrpw, const float* __restrict__ gatew,
    const float* __restrict__ ogwf, const float* __restrict__ opwf,
    short* __restrict__ Wpack, short* __restrict__ ogw, short* __restrict__ opw)
{
  int idx = blockIdx.x*256 + threadIdx.x;
  if (idx < 512*128){
    int r = idx >> 7, k = idx & 127, cc = r >> 1;
    float v = (r & 1) ? gatew[cc*128+k] : lrpw[cc*128+k];
    Wpack[idx] = f2bf(v);
  } else if (idx < 512*128 + 128*128) {
    int j = idx - 512*128; ogw[j] = f2bf(ogwf[j]);
  } else {
    int j = idx - 512*128 - 128*128; opw[j] = f2bf(opwf[j]);
  }
}

// ---------------- stage 1: LN + gated projections -> left_t/right_t (c-major bf16)
__global__ __launch_bounds__(512) void stage1_kernel(
    const float* __restrict__ Zraw, const float* __restrict__ mask,
    const float* __restrict__ ln1w, const float* __restrict__ ln1b,
    const float* __restrict__ lrpb, const float* __restrict__ gateb,
    const short* __restrict__ Wpack,
    short* __restrict__ left, short* __restrict__ right)
{
  __shared__ float zraw[64][132];
  __shared__ short zb[64][136];
  __shared__ float part[64][8][2];
  __shared__ float stats[64][2];

  const int t = threadIdx.x;
  const int pos0 = blockIdx.x * 64;

  // load 64 positions x 128 ch fp32
  const float* Zr = Zraw + (size_t)pos0 * 128;
  #pragma unroll
  for (int i = 0; i < 4; i++) {
    int idx = i*512 + t;
    float4v v = *(const float4v*)(Zr + (size_t)idx*4);
    int row = idx >> 5, col = (idx & 31) << 2;
    *(float4v*)&zraw[row][col] = v;
  }
  __syncthreads();

  // layernorm: 8 threads per position
  {
    int pos = t >> 3, seg = t & 7;
    float s = 0.f, ss = 0.f;
    #pragma unroll
    for (int i = 0; i < 16; i++){ float v = zraw[pos][seg*16+i]; s += v; ss += v*v; }
    part[pos][seg][0] = s; part[pos][seg][1] = ss;
  }
  __syncthreads();
  if ((t & 7) == 0) {
    int pos = t >> 3;
    float S = 0.f, SS = 0.f;
    #pragma unroll
    for (int j = 0; j < 8; j++){ S += part[pos][j][0]; SS += part[pos][j][1]; }
    float m = S * (1.f/128.f);
    float v = SS * (1.f/128.f) - m*m;
    stats[pos][0] = m; stats[pos][1] = rsqrtf(v + LN_EPS);
  }
  __syncthreads();
  {
    int pos = t >> 3, seg = t & 7;
    float m = stats[pos][0], r = stats[pos][1];
    #pragma unroll
    for (int i = 0; i < 16; i++){
      int c = seg*16 + i;
      float v = (zraw[pos][c]-m)*r*ln1w[c] + ln1b[c];
      zb[pos][c] = f2bf(v);
    }
  }
  __syncthreads();

  // GEMM: A = Wpack [512 x 128], B = z^T [128 x 64pos]; wave w owns rows w*64..w*64+63
  const int w = t >> 6, lane = t & 63;
  const int q = lane >> 4, m15 = lane & 15;

  float4v acc[4][4];
  #pragma unroll
  for (int a = 0; a < 4; a++)
    #pragma unroll
    for (int b = 0; b < 4; b++) acc[a][b] = (float4v){0.f,0.f,0.f,0.f};

  #pragma unroll
  for (int s = 0; s < 4; s++){
    short8 af[4], bfv[4];
    #pragma unroll
    for (int rt = 0; rt < 4; rt++)
      af[rt] = *(const short8*)(Wpack + ((size_t)(w*64 + rt*16 + m15))*128 + s*32 + q*8);
    #pragma unroll
    for (int pt = 0; pt < 4; pt++)
      bfv[pt] = *(const short8*)(&zb[pt*16 + m15][s*32 + q*8]);
    #pragma unroll
    for (int rt = 0; rt < 4; rt++)
      #pragma unroll
      for (int pt = 0; pt < 4; pt++)
        acc[rt][pt] = __builtin_amdgcn_mfma_f32_16x16x32_bf16(af[rt], bfv[pt], acc[rt][pt], 0, 0, 0);
  }

  // epilogue: rows 2c (lrp) & 2c+1 (gate) live in the same lane's acc regs
  #pragma unroll
  for (int rt = 0; rt < 4; rt++){
    int rowbase = w*64 + rt*16 + 4*q;  // even
    #pragma unroll
    for (int pt = 0; pt < 4; pt++){
      int pos = pos0 + pt*16 + m15;
      float mk = mask[pos];
      #pragma unroll
      for (int p = 0; p < 2; p++){
        int ch = (rowbase >> 1) + p;
        float lr = acc[rt][pt][2*p]   + lrpb[ch];
        float gt = acc[rt][pt][2*p+1] + gateb[ch];
        float val = lr * mk * sigmoidf_(gt);
        short* dst = (ch < 128) ? (left + (size_t)ch*NP + pos)
                                : (right + (size_t)(ch-128)*NP + pos);
        *dst = f2bf(val);
      }
    }
  }
}

// ---------------- triangle: tri[c] = L_c @ R_c^T  (NT GEMM per c) ----------------
__global__ __launch_bounds__(256) void tri_kernel(
    const short* __restrict__ left, const short* __restrict__ right,
    float* __restrict__ tri)
{
  __shared__ short As[128][72];
  __shared__ short Bs[128][72];

  const int t  = threadIdx.x;
  const int c  = blockIdx.z;
  const int i0 = blockIdx.y * 128;
  const int j0 = blockIdx.x * 128;

  const short* Lp = left  + (size_t)c*NP + (size_t)i0*NN;
  const short* Rp = right + (size_t)c*NP + (size_t)j0*NN;

  const int w = t >> 6, lane = t & 63;
  const int q = lane >> 4, m15 = lane & 15;
  const int wi = w >> 1, wj = w & 1;

  float4v acc[4][4];
  #pragma unroll
  for (int a = 0; a < 4; a++)
    #pragma unroll
    for (int b = 0; b < 4; b++) acc[a][b] = (float4v){0.f,0.f,0.f,0.f};

  for (int it = 0; it < 8; it++){
    const int k0 = it * 64;
    __syncthreads();
    #pragma unroll
    for (int i = 0; i < 4; i++){
      int idx = i*256 + t;
      int row = idx >> 3, c8 = (idx & 7) * 8;
      *(short8*)&As[row][c8] = *(const short8*)(Lp + (size_t)row*NN + k0 + c8);
      *(short8*)&Bs[row][c8] = *(const short8*)(Rp + (size_t)row*NN + k0 + c8);
    }
    __syncthreads();
    #pragma unroll
    for (int s = 0; s < 2; s++){
      short8 af[4], bfv[4];
      #pragma unroll
      for (int mi = 0; mi < 4; mi++)
        af[mi] = *(const short8*)(&As[wi*64 + mi*16 + m15][s*32 + q*8]);
      #pragma unroll
      for (int nj = 0; nj < 4; nj++)
        bfv[nj] = *(const short8*)(&Bs[wj*64 + nj*16 + m15][s*32 + q*8]);
      #pragma unroll
      for (int mi = 0; mi < 4; mi++)
        #pragma unroll
        for (int nj = 0; nj < 4; nj++)
          acc[mi][nj] = __builtin_amdgcn_mfma_f32_16x16x32_bf16(af[mi], bfv[nj], acc[mi][nj], 0, 0, 0);
    }
  }

  float* Tp = tri + (size_t)c*NP;
  #pragma unroll
  for (int mi = 0; mi < 4; mi++)
    #pragma unroll
    for (int nj = 0; nj < 4; nj++)
      #pragma unroll
      for (int r = 0; r < 4; r++){
        int i = i0 + wi*64 + mi*16 + 4*q + r;
        int j = j0 + wj*64 + nj*16 + m15;
        Tp[(size_t)i*NN + j] = acc[mi][nj][r];
      }
}

// ---------------- stage 2: gate + LN + out-proj + residual ----------------
__global__ __launch_bounds__(256) void stage2_kernel(
    const float* __restrict__ tri,
    const short* __restrict__ ogw, const short* __restrict__ opw,
    const float* __restrict__ ogb, const float* __restrict__ ln2w,
    const float* __restrict__ ln2b, const float* __restrict__ outb,
    float* __restrict__ out)
{
  __shared__ short tb[64][136];
  __shared__ short lnb_s[64][136];
  __shared__ float part[64][4][2];
  __shared__ float stats[64][2];

  const int t = threadIdx.x;
  const int pos0 = blockIdx.x * 64;

  // load tri c-stripe [128 c][64 pos], transpose into LDS as bf16 [pos][c]
  #pragma unroll
  for (int i = 0; i < 8; i++){
    int idx = i*256 + t;
    int cc = idx >> 4, p4 = (idx & 15) << 2;
    float4v v = *(const float4v*)(tri + (size_t)cc*NP + pos0 + p4);
    #pragma unroll
    for (int u = 0; u < 4; u++) tb[p4+u][cc] = f2bf(v[u]);
  }
  __syncthreads();

  // LN over c: 4 threads per position
  {
    int pos = t >> 2, seg = t & 3;
    float s = 0.f, ss = 0.f;
    #pragma unroll
    for (int i = 0; i < 32; i++){ float v = bf2f(tb[pos][seg*32+i]); s += v; ss += v*v; }
    part[pos][seg][0] = s; part[pos][seg][1] = ss;
  }
  __syncthreads();
  if ((t & 3) == 0){
    int pos = t >> 2;
    float S = 0.f, SS = 0.f;
    #pragma unroll
    for (int j = 0; j < 4; j++){ S += part[pos][j][0]; SS += part[pos][j][1]; }
    float m = S * (1.f/128.f);
    float v = SS * (1.f/128.f) - m*m;
    stats[pos][0] = m; stats[pos][1] = rsqrtf(v + LN_EPS);
  }
  __syncthreads();
  {
    int pos = t >> 2, seg = t & 3;
    float m = stats[pos][0], r = stats[pos][1];
    #pragma unroll
    for (int i = 0; i < 32; i++){
      int c = seg*32 + i;
      float v = bf2f(tb[pos][c]);
      lnb_s[pos][c] = f2bf((v-m)*r*ln2w[c] + ln2b[c]);
    }
  }
  __syncthreads();

  // two GEMMs: D1[pos][d] = tri_bf16 @ og_w^T ; D2[pos][d] = LN(tri) @ op_w^T
  const int w = t >> 6, lane = t & 63;
  const int q = lane >> 4, m15 = lane & 15;

  float4v a1[2][4], a2[2][4];
  #pragma unroll
  for (int a = 0; a < 2; a++)
    #pragma unroll
    for (int b = 0; b < 4; b++){ a1[a][b] = (float4v){0.f,0.f,0.f,0.f}; a2[a][b] = (float4v){0.f,0.f,0.f,0.f}; }

  #pragma unroll
  for (int s = 0; s < 4; s++){
    short8 af1[4], af2[4], bv1[2], bv2[2];
    #pragma unroll
    for (int pt = 0; pt < 4; pt++){
      af1[pt] = *(const short8*)(&tb[pt*16 + m15][s*32 + q*8]);
      af2[pt] = *(const short8*)(&lnb_s[pt*16 + m15][s*32 + q*8]);
    }
    #pragma unroll
    for (int dt = 0; dt < 2; dt++){
      int d = w*32 + dt*16 + m15;
      bv1[dt] = *(const short8*)(ogw + (size_t)d*128 + s*32 + q*8);
      bv2[dt] = *(const short8*)(opw + (size_t)d*128 + s*32 + q*8);
    }
    #pragma unroll
    for (int dt = 0; dt < 2; dt++)
      #pragma unroll
      for (int pt = 0; pt < 4; pt++){
        a1[dt][pt] = __builtin_amdgcn_mfma_f32_16x16x32_bf16(af1[pt], bv1[dt], a1[dt][pt], 0, 0, 0);
        a2[dt][pt] = __builtin_amdgcn_mfma_f32_16x16x32_bf16(af2[pt], bv2[dt], a2[dt][pt], 0, 0, 0);
      }
  }

  #pragma unroll
  for (int dt = 0; dt < 2; dt++){
    int d = w*32 + dt*16 + m15;
    float ob = ogb[d], xb = outb[d];
    #pragma unroll
    for (int pt = 0; pt < 4; pt++)
      #pragma unroll
      for (int r = 0; r < 4; r++){
        int pos = pt*16 + 4*q + r;
        float trv = bf2f(tb[pos][d]);
        float go = sigmoidf_(a1[dt][pt][r] + ob);
        float z2 = a2[dt][pt][r] + xb;
        out[(size_t)(pos0+pos)*128 + d] = trv + go*z2;
      }
  }
}

extern "C" void kernel_launch(void* const* d_in, const int* in_sizes, int n_in,
                              void* d_out, int out_size, void* d_ws, size_t ws_size,
                              hipStream_t stream)
{
  const float* Zraw = (const float*)d_in[0];
  const float* mask = (const float*)d_in[1];
  const float* ln1w = (const float*)d_in[2];
  const float* ln1b = (const float*)d_in[3];
  const float* lrpw = (const float*)d_in[4];
  const float* lrpb = (const float*)d_in[5];
  const float* gatew= (const float*)d_in[6];
  const float* gateb= (const float*)d_in[7];
  const float* ogwf = (const float*)d_in[8];
  const float* ogb  = (const float*)d_in[9];
  const float* ln2w = (const float*)d_in[10];
  const float* ln2b = (const float*)d_in[11];
  const float* opwf = (const float*)d_in[12];
  const float* outb = (const float*)d_in[13];
  float* out = (float*)d_out;

  short* left  = (short*)d_ws;                       // 128*NP bf16
  short* right = left + (size_t)128*NP;              // 128*NP bf16
  float* tri   = (float*)(right + (size_t)128*NP);   // 128*NP fp32
  short* Wpack = (short*)(tri + (size_t)128*NP);     // 512*128 bf16
  short* ogw   = Wpack + 512*128;                    // 128*128 bf16
  short* opw   = ogw + 128*128;                      // 128*128 bf16

  hipLaunchKernelGGL(prep_kernel, dim3(384), dim3(256), 0, stream,
                     lrpw, gatew, ogwf, opwf, Wpack, ogw, opw);
  hipLaunchKernelGGL(stage1_kernel, dim3(NP/64), dim3(512), 0, stream,
                     Zraw, mask, ln1w, ln1b, lrpb, gateb, Wpack, left, right);
  hipLaunchKernelGGL(tri_kernel, dim3(4, 4, 128), dim3(256), 0, stream,
                     left, right, tri);
  hipLaunchKernelGGL(stage2_kernel, dim3(NP/64), dim3(256), 0, stream,
                     tri, ogw, opw, ogb, ln2w, ln2b, outb, out);
}

// Round 2
// 460.532 us; speedup vs baseline: 1.1682x; 1.1682x over previous
//
#include <hip/hip_runtime.h>

#define NN 512
#define NP (NN*NN)
#define LN_EPS 1e-5f

typedef __attribute__((ext_vector_type(8))) short short8;
typedef __attribute__((ext_vector_type(4))) float float4v;

__device__ __forceinline__ short f2bf(float x){
  union { float f; unsigned u; } un; un.f = x;
  unsigned r = un.u + 0x7fffu + ((un.u >> 16) & 1u);
  return (short)(r >> 16);
}
__device__ __forceinline__ float bf2f(short b){
  union { unsigned u; float f; } un; un.u = ((unsigned)(unsigned short)b) << 16;
  return un.f;
}
__device__ __forceinline__ float sigmoidf_(float x){ return 1.f/(1.f+__expf(-x)); }

// async global->LDS, 16B per lane; LDS dest must be wave-uniform (lane*16 is implicit)
__device__ __forceinline__ void gl2lds16(const short* g, short* l){
  __builtin_amdgcn_global_load_lds((const __attribute__((address_space(1))) void*)g,
                                   (__attribute__((address_space(3))) void*)l, 16, 0, 0);
}

// ---------------- prep: convert weights to bf16, interleave lrp/gate ----------
__global__ __launch_bounds__(256) void prep_kernel(
    const float* __restrict__ lrpw, const float* __restrict__ gatew,
    const float* __restrict__ ogwf, const float* __restrict__ opwf,
    short* __restrict__ Wpack, short* __restrict__ ogw, short* __restrict__ opw)
{
  int idx = blockIdx.x*256 + threadIdx.x;
  if (idx < 512*128){
    int r = idx >> 7, k = idx & 127, cc = r >> 1;
    float v = (r & 1) ? gatew[cc*128+k] : lrpw[cc*128+k];
    Wpack[idx] = f2bf(v);
  } else if (idx < 512*128 + 128*128) {
    int j = idx - 512*128; ogw[j] = f2bf(ogwf[j]);
  } else {
    int j = idx - 512*128 - 128*128; opw[j] = f2bf(opwf[j]);
  }
}

// ---------------- stage 1: LN (shuffle-based) + gated projections ----------------
__global__ __launch_bounds__(512) void stage1_kernel(
    const float* __restrict__ Zraw, const float* __restrict__ mask,
    const float* __restrict__ ln1w, const float* __restrict__ ln1b,
    const float* __restrict__ lrpb, const float* __restrict__ gateb,
    const short* __restrict__ Wpack,
    short* __restrict__ left, short* __restrict__ right)
{
  __shared__ short zb[64][136];   // row stride 272B: b128 reads hit each bank exactly 8x

  const int t = threadIdx.x;
  const int pos0 = blockIdx.x * 64;
  const int pos = t >> 3, seg = t & 7;   // 8 lanes per position (within one wave)

  // load 16 fp32 channels straight to registers
  const float* zp = Zraw + (size_t)(pos0 + pos)*128 + seg*16;
  float x[16];
  #pragma unroll
  for (int i = 0; i < 4; i++){
    float4v v = *(const float4v*)(zp + i*4);
    x[4*i] = v[0]; x[4*i+1] = v[1]; x[4*i+2] = v[2]; x[4*i+3] = v[3];
  }
  float s = 0.f, ss = 0.f;
  #pragma unroll
  for (int i = 0; i < 16; i++){ s += x[i]; ss += x[i]*x[i]; }
  // reduce across the 8 lanes sharing this position
  #pragma unroll
  for (int off = 1; off < 8; off <<= 1){
    s  += __shfl_xor(s,  off);
    ss += __shfl_xor(ss, off);
  }
  float m = s * (1.f/128.f);
  float r = rsqrtf(ss * (1.f/128.f) - m*m + LN_EPS);

  short8 o0, o1;
  #pragma unroll
  for (int i = 0; i < 8; i++){
    int c = seg*16 + i;
    o0[i] = f2bf((x[i]-m)*r*ln1w[c] + ln1b[c]);
  }
  #pragma unroll
  for (int i = 0; i < 8; i++){
    int c = seg*16 + 8 + i;
    o1[i] = f2bf((x[8+i]-m)*r*ln1w[c] + ln1b[c]);
  }
  *(short8*)&zb[pos][seg*16]     = o0;
  *(short8*)&zb[pos][seg*16 + 8] = o1;
  __syncthreads();

  // GEMM: A = Wpack [512 x 128], B = z^T [128 x 64]; wave w owns rows w*64..+63
  const int w = t >> 6, lane = t & 63;
  const int q = lane >> 4, m15 = lane & 15;

  float4v acc[4][4];
  #pragma unroll
  for (int a = 0; a < 4; a++)
    #pragma unroll
    for (int b = 0; b < 4; b++) acc[a][b] = (float4v){0.f,0.f,0.f,0.f};

  #pragma unroll
  for (int sstep = 0; sstep < 4; sstep++){
    short8 af[4], bfv[4];
    #pragma unroll
    for (int rt = 0; rt < 4; rt++)
      af[rt] = *(const short8*)(Wpack + ((size_t)(w*64 + rt*16 + m15))*128 + sstep*32 + q*8);
    #pragma unroll
    for (int pt = 0; pt < 4; pt++)
      bfv[pt] = *(const short8*)(&zb[pt*16 + m15][sstep*32 + q*8]);
    #pragma unroll
    for (int rt = 0; rt < 4; rt++)
      #pragma unroll
      for (int pt = 0; pt < 4; pt++)
        acc[rt][pt] = __builtin_amdgcn_mfma_f32_16x16x32_bf16(af[rt], bfv[pt], acc[rt][pt], 0, 0, 0);
  }

  // epilogue: rows 2c (lrp) & 2c+1 (gate) live in the same lane's acc regs
  #pragma unroll
  for (int rt = 0; rt < 4; rt++){
    int rowbase = w*64 + rt*16 + 4*q;  // even
    #pragma unroll
    for (int pt = 0; pt < 4; pt++){
      int posj = pos0 + pt*16 + m15;
      float mk = mask[posj];
      #pragma unroll
      for (int p = 0; p < 2; p++){
        int ch = (rowbase >> 1) + p;
        float lr = acc[rt][pt][2*p]   + lrpb[ch];
        float gt = acc[rt][pt][2*p+1] + gateb[ch];
        float val = lr * mk * sigmoidf_(gt);
        short* dst = (ch < 128) ? (left + (size_t)ch*NP + posj)
                                : (right + (size_t)(ch-128)*NP + posj);
        *dst = f2bf(val);
      }
    }
  }
}

// ---------------- triangle: tri[c] = L_c @ R_c^T, m97-style async staging ----------
__global__ __launch_bounds__(256) void tri_kernel(
    const short* __restrict__ left, const short* __restrict__ right,
    short* __restrict__ tri_bf)
{
  // unpadded (global_load_lds is lane-linear); XOR-swizzled 16B units instead
  __shared__ short As[128][64];
  __shared__ short Bs[128][64];

  const int t  = threadIdx.x;
  const int c  = blockIdx.z;
  const int i0 = blockIdx.y * 128;
  const int j0 = blockIdx.x * 128;

  const int w = t >> 6, lane = t & 63;
  const int q = lane >> 4, m15 = lane & 15;
  const int wi = w >> 1, wj = w & 1;

  // staging: wave w fills rows [w*32, w*32+32) of As and Bs, 8 rows per instruction.
  // lane -> row = chunkbase + (lane>>3), physical 16B-unit = lane&7,
  // logical unit = phys ^ (row&7)  (conflict-free swizzle)
  const int lrow = lane >> 3;
  const int lu   = (lane & 7) ^ lrow;
  const short* Lsrc = left  + (size_t)c*NP + (size_t)(i0 + w*32 + lrow)*NN + lu*8;
  const short* Rsrc = right + (size_t)c*NP + (size_t)(j0 + w*32 + lrow)*NN + lu*8;

  float4v acc[4][4];
  #pragma unroll
  for (int a = 0; a < 4; a++)
    #pragma unroll
    for (int b = 0; b < 4; b++) acc[a][b] = (float4v){0.f,0.f,0.f,0.f};

  for (int it = 0; it < 8; it++){
    const int k0 = it * 64;
    __syncthreads();
    #pragma unroll
    for (int i = 0; i < 4; i++){
      gl2lds16(Lsrc + (size_t)i*8*NN + k0, &As[w*32 + i*8][0]);
      gl2lds16(Rsrc + (size_t)i*8*NN + k0, &Bs[w*32 + i*8][0]);
    }
    __syncthreads();
    #pragma unroll
    for (int s = 0; s < 2; s++){
      short8 af[4], bfv[4];
      #pragma unroll
      for (int mi = 0; mi < 4; mi++)
        af[mi] = *(const short8*)(&As[wi*64 + mi*16 + m15][((s*4 + q) ^ (m15 & 7))*8]);
      #pragma unroll
      for (int nj = 0; nj < 4; nj++)
        bfv[nj] = *(const short8*)(&Bs[wj*64 + nj*16 + m15][((s*4 + q) ^ (m15 & 7))*8]);
      #pragma unroll
      for (int mi = 0; mi < 4; mi++)
        #pragma unroll
        for (int nj = 0; nj < 4; nj++)
          acc[mi][nj] = __builtin_amdgcn_mfma_f32_16x16x32_bf16(af[mi], bfv[nj], acc[mi][nj], 0, 0, 0);
    }
  }

  short* Tp = tri_bf + (size_t)c*NP;
  #pragma unroll
  for (int mi = 0; mi < 4; mi++)
    #pragma unroll
    for (int nj = 0; nj < 4; nj++)
      #pragma unroll
      for (int r = 0; r < 4; r++){
        int i = i0 + wi*64 + mi*16 + 4*q + r;
        int j = j0 + wj*64 + nj*16 + m15;
        Tp[(size_t)i*NN + j] = f2bf(acc[mi][nj][r]);
      }
}

// ---------------- stage 2: gate + LN + out-proj + residual ----------------
__global__ __launch_bounds__(256) void stage2_kernel(
    const short* __restrict__ tri_bf,
    const short* __restrict__ ogw, const short* __restrict__ opw,
    const float* __restrict__ ogb, const float* __restrict__ ln2w,
    const float* __restrict__ ln2b, const float* __restrict__ outb,
    float* __restrict__ out)
{
  __shared__ short tb[64][136];
  __shared__ short lnb_s[64][136];
  __shared__ float part[64][9];   // stride 9 dwords == 1 mod 32 banks -> conflict-free

  const int t = threadIdx.x;
  const int pos0 = blockIdx.x * 64;
  const int lane = t & 63, w = t >> 6;

  // thread owns position 'lane', channels [w*32, w*32+32); coalesced 128B loads
  short8 pk[4];
  float s = 0.f, ss = 0.f;
  #pragma unroll
  for (int u = 0; u < 4; u++){
    short8 p;
    #pragma unroll
    for (int j = 0; j < 8; j++){
      int cc = w*32 + u*8 + j;
      short b = tri_bf[(size_t)cc*NP + pos0 + lane];
      p[j] = b;
      float v = bf2f(b); s += v; ss += v*v;
    }
    pk[u] = p;
    *(short8*)&tb[lane][w*32 + u*8] = p;   // conflict-free b128 (banks hit exactly 8x)
  }
  part[lane][2*w]   = s;
  part[lane][2*w+1] = ss;
  __syncthreads();

  float S = 0.f, SS = 0.f;
  #pragma unroll
  for (int j = 0; j < 4; j++){ S += part[lane][2*j]; SS += part[lane][2*j+1]; }
  float m = S * (1.f/128.f);
  float r = rsqrtf(SS * (1.f/128.f) - m*m + LN_EPS);
  #pragma unroll
  for (int u = 0; u < 4; u++){
    short8 p = pk[u], o;
    #pragma unroll
    for (int j = 0; j < 8; j++){
      int cc = w*32 + u*8 + j;
      float v = bf2f(p[j]);
      o[j] = f2bf((v - m)*r*ln2w[cc] + ln2b[cc]);
    }
    *(short8*)&lnb_s[lane][w*32 + u*8] = o;
  }
  __syncthreads();

  // two GEMMs: D1[pos][d] = tri_bf16 @ og_w^T ; D2[pos][d] = LN(tri) @ op_w^T
  const int q = lane >> 4, m15 = lane & 15;

  float4v a1[2][4], a2[2][4];
  #pragma unroll
  for (int a = 0; a < 2; a++)
    #pragma unroll
    for (int b = 0; b < 4; b++){ a1[a][b] = (float4v){0.f,0.f,0.f,0.f}; a2[a][b] = (float4v){0.f,0.f,0.f,0.f}; }

  #pragma unroll
  for (int sstep = 0; sstep < 4; sstep++){
    short8 af1[4], af2[4], bv1[2], bv2[2];
    #pragma unroll
    for (int pt = 0; pt < 4; pt++){
      af1[pt] = *(const short8*)(&tb[pt*16 + m15][sstep*32 + q*8]);
      af2[pt] = *(const short8*)(&lnb_s[pt*16 + m15][sstep*32 + q*8]);
    }
    #pragma unroll
    for (int dt = 0; dt < 2; dt++){
      int d = w*32 + dt*16 + m15;
      bv1[dt] = *(const short8*)(ogw + (size_t)d*128 + sstep*32 + q*8);
      bv2[dt] = *(const short8*)(opw + (size_t)d*128 + sstep*32 + q*8);
    }
    #pragma unroll
    for (int dt = 0; dt < 2; dt++)
      #pragma unroll
      for (int pt = 0; pt < 4; pt++){
        a1[dt][pt] = __builtin_amdgcn_mfma_f32_16x16x32_bf16(af1[pt], bv1[dt], a1[dt][pt], 0, 0, 0);
        a2[dt][pt] = __builtin_amdgcn_mfma_f32_16x16x32_bf16(af2[pt], bv2[dt], a2[dt][pt], 0, 0, 0);
      }
  }

  #pragma unroll
  for (int dt = 0; dt < 2; dt++){
    int d = w*32 + dt*16 + m15;
    float ob = ogb[d], xb = outb[d];
    #pragma unroll
    for (int pt = 0; pt < 4; pt++)
      #pragma unroll
      for (int r2 = 0; r2 < 4; r2++){
        int pos = pt*16 + 4*q + r2;
        float trv = bf2f(tb[pos][d]);
        float go = sigmoidf_(a1[dt][pt][r2] + ob);
        float z2 = a2[dt][pt][r2] + xb;
        out[(size_t)(pos0+pos)*128 + d] = trv + go*z2;
      }
  }
}

extern "C" void kernel_launch(void* const* d_in, const int* in_sizes, int n_in,
                              void* d_out, int out_size, void* d_ws, size_t ws_size,
                              hipStream_t stream)
{
  const float* Zraw = (const float*)d_in[0];
  const float* mask = (const float*)d_in[1];
  const float* ln1w = (const float*)d_in[2];
  const float* ln1b = (const float*)d_in[3];
  const float* lrpw = (const float*)d_in[4];
  const float* lrpb = (const float*)d_in[5];
  const float* gatew= (const float*)d_in[6];
  const float* gateb= (const float*)d_in[7];
  const float* ogwf = (const float*)d_in[8];
  const float* ogb  = (const float*)d_in[9];
  const float* ln2w = (const float*)d_in[10];
  const float* ln2b = (const float*)d_in[11];
  const float* opwf = (const float*)d_in[12];
  const float* outb = (const float*)d_in[13];
  float* out = (float*)d_out;

  short* left   = (short*)d_ws;                      // 128*NP bf16
  short* right  = left + (size_t)128*NP;             // 128*NP bf16
  short* tri_bf = right + (size_t)128*NP;            // 128*NP bf16
  short* Wpack  = tri_bf + (size_t)128*NP;           // 512*128 bf16
  short* ogw    = Wpack + 512*128;                   // 128*128 bf16
  short* opw    = ogw + 128*128;                     // 128*128 bf16

  hipLaunchKernelGGL(prep_kernel, dim3(384), dim3(256), 0, stream,
                     lrpw, gatew, ogwf, opwf, Wpack, ogw, opw);
  hipLaunchKernelGGL(stage1_kernel, dim3(NP/64), dim3(512), 0, stream,
                     Zraw, mask, ln1w, ln1b, lrpb, gateb, Wpack, left, right);
  hipLaunchKernelGGL(tri_kernel, dim3(4, 4, 128), dim3(256), 0, stream,
                     left, right, tri_bf);
  hipLaunchKernelGGL(stage2_kernel, dim3(NP/64), dim3(256), 0, stream,
                     tri_bf, ogw, opw, ogb, ln2w, ln2b, outb, out);
}